// Round 18
// baseline (178.914 us; speedup 1.0000x reference)
//
#include <hip/hip_runtime.h>
#include <hip/hip_bf16.h>
#include <math.h>

typedef __attribute__((ext_vector_type(8))) short bf16x8;   // 8 bf16 = 4 VGPR
typedef __attribute__((ext_vector_type(4))) float f32x4;
typedef __attribute__((ext_vector_type(16))) float f32x16;
typedef __attribute__((ext_vector_type(4))) unsigned int u32x4;

static constexpr int Mtot = 8192;   // B*S
static constexpr int Dmod = 1024;
static constexpr int SEQ  = 2048;
static constexpr int NH   = 16;
static constexpr int DH   = 64;

// softmax scale folded into Q projection, in exp2 domain: (1/8) * log2(e)
static constexpr float QSCALE = 0.18033688011112042f;

// fp32 -> bf16 RNE
__device__ __forceinline__ unsigned short f2bf(float x) {
    unsigned int u = __float_as_uint(x);
    u += 0x7fff + ((u >> 16) & 1);
    return (unsigned short)(u >> 16);
}

__device__ __forceinline__ float bf2f(short s) {
    return __uint_as_float(((unsigned int)(unsigned short)s) << 16);
}

// async global->LDS, 16B per lane. LDS dest = wave-uniform base + lane*16.
__device__ __forceinline__ void gload_lds16(const void* g, void* l) {
    __builtin_amdgcn_global_load_lds(
        (const __attribute__((address_space(1))) unsigned int*)g,
        (__attribute__((address_space(3))) unsigned int*)l, 16, 0, 0);
}

// ---------------------------------------------------------------------------
// x fp32 -> bf16
// ---------------------------------------------------------------------------
__global__ __launch_bounds__(256)
void cvt_bf16(const float* __restrict__ in, unsigned short* __restrict__ out, int n4) {
    int i = blockIdx.x * blockDim.x + threadIdx.x;
    const int stride = gridDim.x * blockDim.x;
    for (; i < n4; i += stride) {
        float4 v = ((const float4*)in)[i];
        ushort4 o;
        o.x = f2bf(v.x); o.y = f2bf(v.y); o.z = f2bf(v.z); o.w = f2bf(v.w);
        ((ushort4*)out)[i] = o;
    }
}

// ---------------------------------------------------------------------------
// All four W[k][n] fp32 -> Wt[n][k] bf16 in one launch (z = which weight)
// ---------------------------------------------------------------------------
__global__ __launch_bounds__(256)
void transpose_cvt4(const float* __restrict__ W0, const float* __restrict__ W1,
                    const float* __restrict__ W2, const float* __restrict__ W3,
                    unsigned short* __restrict__ T0, unsigned short* __restrict__ T1,
                    unsigned short* __restrict__ T2, unsigned short* __restrict__ T3) {
    __shared__ float tile[64][68];
    const int z = blockIdx.z;
    const float* W = z == 0 ? W0 : z == 1 ? W1 : z == 2 ? W2 : W3;
    unsigned short* Wt = z == 0 ? T0 : z == 1 ? T1 : z == 2 ? T2 : T3;

    const int n0 = blockIdx.x * 64, k0 = blockIdx.y * 64;
    const int t = threadIdx.x;
    const int r = t >> 4, c4 = (t & 15) * 4;
#pragma unroll
    for (int i = 0; i < 4; ++i) {
        float4 v = *(const float4*)&W[(size_t)(k0 + r + i * 16) * Dmod + n0 + c4];
        tile[c4 + 0][r + i * 16] = v.x;
        tile[c4 + 1][r + i * 16] = v.y;
        tile[c4 + 2][r + i * 16] = v.z;
        tile[c4 + 3][r + i * 16] = v.w;
    }
    __syncthreads();
#pragma unroll
    for (int i = 0; i < 4; ++i) {
        ushort4 o;
        o.x = f2bf(tile[r + i * 16][c4 + 0]);
        o.y = f2bf(tile[r + i * 16][c4 + 1]);
        o.z = f2bf(tile[r + i * 16][c4 + 2]);
        o.w = f2bf(tile[r + i * 16][c4 + 3]);
        *(ushort4*)&Wt[(size_t)(n0 + r + i * 16) * Dmod + k0 + c4] = o;
    }
}

// ---------------------------------------------------------------------------
// 8-phase GEMM (T3+T4). MODE0: 256x256 tile (qkv, N=3072, 384 blocks).
// MODE1: 128x256 tile (out proj, 256 blocks = full GPU).
// BK=64, 8 waves, LDS dbuf, counted vmcnt (MODE0:6, MODE1:4).
// ---------------------------------------------------------------------------
template<int MODE>
__global__ __launch_bounds__(512)
void gemm256(const unsigned short* __restrict__ A,
             const unsigned short* __restrict__ Bw,
             const float* __restrict__ bias,
             unsigned short* __restrict__ Qb,
             unsigned short* __restrict__ Kb,
             unsigned short* __restrict__ Vtb,
             float* __restrict__ Fout) {
    constexpr int MF   = MODE == 0 ? 8 : 4;        // m-fragments per wave
    constexpr int AHB  = MODE == 0 ? 16384 : 8192; // A half-tile bytes
    constexpr int ALD  = MODE == 0 ? 2 : 1;        // loads per A-stage
    constexpr int OFF_A0 = 0, OFF_B0 = AHB, OFF_A1 = AHB + 16384, OFF_B1 = 2 * AHB + 16384;
    constexpr int BUFB = 2 * AHB + 32768;
    constexpr int NTN  = MODE == 0 ? 12 : 4;
    constexpr int MPX  = MODE == 0 ? 4 : 8;        // m-tiles per XCD

    __shared__ __align__(16) char lds[2 * BUFB];

    const int id  = blockIdx.x;
    const int xcd = id & 7, idx = id >> 3;
    const int mt = xcd * MPX + idx / NTN;
    const int nt = idx % NTN;
    const int m0 = mt * (MF * 32), n0 = nt * 256;

    const int t = threadIdx.x;
    const int wid = t >> 6, l = t & 63;
    const int wm = wid >> 2, wn = wid & 3;
    const int r16 = l & 15, g = l >> 4;

    auto stageA = [&](int kt, int kh, int regionOff) {
        char* dst = lds + regionOff + wid * 1024;
#pragma unroll
        for (int r = 0; r < ALD; ++r) {
            const int o  = r * 8192 + t * 16;
            const int lg = o ^ (((o >> 7) & 3) << 4);
            gload_lds16((const char*)A + (size_t)(m0 + (lg >> 6)) * 2048
                            + kt * 128 + kh * 64 + (lg & 63),
                        dst + r * 8192);
        }
    };
    auto stageB = [&](int kt, int kh, int regionOff) {
        char* dst = lds + regionOff + wid * 1024;
#pragma unroll
        for (int r = 0; r < 2; ++r) {
            const int o  = r * 8192 + t * 16;
            const int lg = o ^ (((o >> 7) & 3) << 4);
            gload_lds16((const char*)Bw + (size_t)(n0 + (lg >> 6)) * 2048
                            + kt * 128 + kh * 64 + (lg & 63),
                        dst + r * 8192);
        }
    };

    f32x4 acc[MF][4];
    const f32x4 z = {0.f, 0.f, 0.f, 0.f};
#pragma unroll
    for (int i = 0; i < MF; ++i)
#pragma unroll
        for (int j = 0; j < 4; ++j) acc[i][j] = z;

    // prologue (issue order fixes vmcnt bookkeeping): A0, B0, A1, B1
    stageA(0, 0, OFF_A0);
    stageB(0, 0, OFF_B0);
    stageA(0, 1, OFF_A1);
    stageB(0, 1, OFF_B1);

    const int arow0 = wm * (MF * 16) + r16;
    const int brow0 = wn * 64 + r16;
    const int gb = g * 16;

    auto gate = [&]() {
        if constexpr (MODE == 0) asm volatile("s_waitcnt vmcnt(6)" ::: "memory");
        else                     asm volatile("s_waitcnt vmcnt(4)" ::: "memory");
        __builtin_amdgcn_s_barrier();
    };

    for (int kt = 0; kt < 16; ++kt) {
        const int buf  = (kt & 1) * BUFB;
        const int nbuf = buf ^ BUFB;
        const int ktn  = kt < 15 ? kt + 1 : 15;   // clamp keeps vmcnt uniform
        bf16x8 af[MF], bv[2];

        // ===== phase 0: kh0, n-frags 0..1 =====
        stageA(ktn, 0, nbuf + OFF_A0);
        gate();
#pragma unroll
        for (int mi = 0; mi < MF; ++mi) {
            const int row = arow0 + mi * 16;
            af[mi] = *(const bf16x8*)(lds + buf + OFF_A0
                      + ((row * 64 + gb) ^ (((row >> 1) & 3) << 4)));
        }
#pragma unroll
        for (int ni = 0; ni < 2; ++ni) {
            const int row = brow0 + ni * 16;
            bv[ni] = *(const bf16x8*)(lds + buf + OFF_B0
                      + ((row * 64 + gb) ^ (((row >> 1) & 3) << 4)));
        }
        asm volatile("s_waitcnt lgkmcnt(0)" ::: "memory");
        __builtin_amdgcn_sched_barrier(0);
        __builtin_amdgcn_s_setprio(1);
#pragma unroll
        for (int mi = 0; mi < MF; ++mi)
#pragma unroll
            for (int ni = 0; ni < 2; ++ni)
                acc[mi][ni] = __builtin_amdgcn_mfma_f32_16x16x32_bf16(
                    af[mi], bv[ni], acc[mi][ni], 0, 0, 0);
        __builtin_amdgcn_s_setprio(0);

        // ===== phase 1: kh0, n-frags 2..3 (reuse af) =====
        stageB(ktn, 0, nbuf + OFF_B0);
#pragma unroll
        for (int ni = 0; ni < 2; ++ni) {
            const int row = brow0 + (2 + ni) * 16;
            bv[ni] = *(const bf16x8*)(lds + buf + OFF_B0
                      + ((row * 64 + gb) ^ (((row >> 1) & 3) << 4)));
        }
        asm volatile("s_waitcnt lgkmcnt(0)" ::: "memory");
        __builtin_amdgcn_sched_barrier(0);
        __builtin_amdgcn_s_setprio(1);
#pragma unroll
        for (int mi = 0; mi < MF; ++mi)
#pragma unroll
            for (int ni = 0; ni < 2; ++ni)
                acc[mi][2 + ni] = __builtin_amdgcn_mfma_f32_16x16x32_bf16(
                    af[mi], bv[ni], acc[mi][2 + ni], 0, 0, 0);
        __builtin_amdgcn_s_setprio(0);

        // ===== phase 2: kh1, n-frags 0..1 =====
        stageA(ktn, 1, nbuf + OFF_A1);
        gate();
#pragma unroll
        for (int mi = 0; mi < MF; ++mi) {
            const int row = arow0 + mi * 16;
            af[mi] = *(const bf16x8*)(lds + buf + OFF_A1
                      + ((row * 64 + gb) ^ (((row >> 1) & 3) << 4)));
        }
#pragma unroll
        for (int ni = 0; ni < 2; ++ni) {
            const int row = brow0 + ni * 16;
            bv[ni] = *(const bf16x8*)(lds + buf + OFF_B1
                      + ((row * 64 + gb) ^ (((row >> 1) & 3) << 4)));
        }
        asm volatile("s_waitcnt lgkmcnt(0)" ::: "memory");
        __builtin_amdgcn_sched_barrier(0);
        __builtin_amdgcn_s_setprio(1);
#pragma unroll
        for (int mi = 0; mi < MF; ++mi)
#pragma unroll
            for (int ni = 0; ni < 2; ++ni)
                acc[mi][ni] = __builtin_amdgcn_mfma_f32_16x16x32_bf16(
                    af[mi], bv[ni], acc[mi][ni], 0, 0, 0);
        __builtin_amdgcn_s_setprio(0);

        // ===== phase 3: kh1, n-frags 2..3 (reuse af) =====
        stageB(ktn, 1, nbuf + OFF_B1);
#pragma unroll
        for (int ni = 0; ni < 2; ++ni) {
            const int row = brow0 + (2 + ni) * 16;
            bv[ni] = *(const bf16x8*)(lds + buf + OFF_B1
                      + ((row * 64 + gb) ^ (((row >> 1) & 3) << 4)));
        }
        asm volatile("s_waitcnt lgkmcnt(0)" ::: "memory");
        __builtin_amdgcn_sched_barrier(0);
        __builtin_amdgcn_s_setprio(1);
#pragma unroll
        for (int mi = 0; mi < MF; ++mi)
#pragma unroll
            for (int ni = 0; ni < 2; ++ni)
                acc[mi][2 + ni] = __builtin_amdgcn_mfma_f32_16x16x32_bf16(
                    af[mi], bv[ni], acc[mi][2 + ni], 0, 0, 0);
        __builtin_amdgcn_s_setprio(0);
    }

    // ===== epilogue =====
    if constexpr (MODE == 0) {
        const int region = n0 >> 10;             // 0=Q, 1=K, 2=V
        if (region <= 1) {
            unsigned short* outp = region ? Kb : Qb;
            const float qs = region == 0 ? QSCALE : 1.0f;
#pragma unroll
            for (int mi = 0; mi < MF; ++mi) {
                const int mrow = m0 + wm * (MF * 16) + mi * 16 + g * 4;
#pragma unroll
                for (int ni = 0; ni < 4; ++ni) {
                    const int ncol = (n0 & 1023) + wn * 64 + ni * 16 + r16;
#pragma unroll
                    for (int reg = 0; reg < 4; ++reg)
                        outp[(size_t)(mrow + reg) * Dmod + ncol] = f2bf(acc[mi][ni][reg] * qs);
                }
            }
        } else {
#pragma unroll
            for (int mi = 0; mi < MF; ++mi) {
                const int mrow = m0 + wm * (MF * 16) + mi * 16 + g * 4;
                const int bidx = mrow >> 11, s = mrow & 2047;
#pragma unroll
                for (int ni = 0; ni < 4; ++ni) {
                    const int n = (n0 & 1023) + wn * 64 + ni * 16 + r16;
                    const int bh = bidx * NH + (n >> 6), d = n & 63;
                    ushort4 o;
                    o.x = f2bf(acc[mi][ni][0]); o.y = f2bf(acc[mi][ni][1]);
                    o.z = f2bf(acc[mi][ni][2]); o.w = f2bf(acc[mi][ni][3]);
                    *(ushort4*)&Vtb[((size_t)bh * DH + d) * SEQ + s] = o;
                }
            }
        }
    } else {
        float bb[4];
#pragma unroll
        for (int ni = 0; ni < 4; ++ni)
            bb[ni] = bias[n0 + wn * 64 + ni * 16 + r16];
#pragma unroll
        for (int mi = 0; mi < MF; ++mi) {
            const int mrow = m0 + wm * (MF * 16) + mi * 16 + g * 4;
#pragma unroll
            for (int ni = 0; ni < 4; ++ni) {
                const int ncol = n0 + wn * 64 + ni * 16 + r16;
#pragma unroll
                for (int reg = 0; reg < 4; ++reg)
                    Fout[(size_t)(mrow + reg) * Dmod + ncol] = acc[mi][ni][reg] + bb[ni];
            }
        }
    }
}

// ---------------------------------------------------------------------------
// MFMA flash attention v6.1: 3-way kv-residue split, launch_bounds(256,4).
//  Round-14 kernel (functionally verified, absmax 0.0078) died ONLY from
//  (256,6) -> VGPR 40 spills. (256,4) keeps the proven 64-VGPR allocation;
//  HW residency is then LDS-capped at 6 blocks/CU for the 1536-block grid
//  (6 x 24.6KB = 147.5 <= 160; 6 waves/SIMD x 64 VGPR = 384 <= 512).
//  * kv-tiles jt === e (mod 3); <= 12 tiles/block critical path.
//  * Fixed exp2-domain max m=4; K dbuf + V single; counted vmcnt ledger.
// ---------------------------------------------------------------------------
__global__ __launch_bounds__(256, 4)
void attn_mfma(const unsigned short* __restrict__ Qg,
               const unsigned short* __restrict__ Kg,
               const unsigned short* __restrict__ Vtg,
               unsigned short* __restrict__ pO0,
               unsigned short* __restrict__ pO1,
               unsigned short* __restrict__ pO2,
               float* __restrict__ pL) {
    __shared__ __align__(16) short Ks[2][64 * 64];   // 16 KB (dbuf)
    __shared__ __align__(16) short Vs[64 * 64];      //  8 KB (single, Vt [d][kv])

    const int id   = blockIdx.x;                   // 0..1535
    const int xcd  = id & 7;
    const int rest = id >> 3;                      // 0..191
    const int bh   = ((rest / 24) << 3) | xcd;     // XCD-local heads
    const int mid  = rest % 24;
    const int pidx = mid / 3;
    const int e    = mid % 3;                      // kv-tile residue (mod 3)
    const int b = bh >> 4, h = bh & 15;
    const int t = threadIdx.x, wid = t >> 6, l = t & 63;
    const int lo = l & 31, hi = l >> 5;
    const int srow8 = t >> 3, scolb = (t & 7) * 16;

    // per-lane staging base offsets (32-bit: buffers are 16.8 MB)
    unsigned int kbase[2], vbase[2];
#pragma unroll
    for (int c = 0; c < 2; ++c) {
        const int row = c * 32 + srow8;
        const int swz = scolb ^ ((row & 7) << 4);
        kbase[c] = (unsigned int)(((b * SEQ + row) * Dmod + h * DH) * 2 + swz);
        vbase[c] = (unsigned int)(((bh * DH + row) * SEQ) * 2 + swz);
    }

    auto stageK = [&](int jt, int buf) {
#pragma unroll
        for (int c = 0; c < 2; ++c)
            gload_lds16((const char*)Kg + kbase[c] + ((size_t)jt << 17),
                        (char*)&Ks[buf][0] + c * 4096 + wid * 1024);
    };
    auto stageV = [&](int jt) {
#pragma unroll
        for (int c = 0; c < 2; ++c)
            gload_lds16((const char*)Vtg + vbase[c] + ((size_t)jt << 7),
                        (char*)&Vs[0] + c * 4096 + wid * 1024);
    };

    unsigned short* const pO = e == 0 ? pO0 : (e == 1 ? pO1 : pO2);

    for (int pass = 0; pass < 2; ++pass) {
        const int qt = pass ? pidx : 15 - pidx;   // heavy tile first
        const int qw0 = qt * 128 + wid * 32;
        const int qg = qw0 + lo;                  // this lane's q row (S^T col)
        const int jmax = 2 * qt + 1;

        __syncthreads();                          // prev pass LDS reads done
        // Q fragments straight from global (B-operand: col=q=lane&31, k=d)
        bf16x8 bq[4];
#pragma unroll
        for (int dc = 0; dc < 4; ++dc)
            bq[dc] = *(const bf16x8*)&Qg[(size_t)(b * SEQ + qg) * Dmod + h * DH + dc * 16 + 8 * hi];
        stageK(e, 0);
        stageV(e);
        __syncthreads();                          // vmcnt(0) drain: K,V landed

        float l_run = 0.f;
        f32x16 oacc0, oacc1;
#pragma unroll
        for (int r = 0; r < 16; ++r) { oacc0[r] = 0.f; oacc1[r] = 0.f; }

        int cur = 0;
        for (int jt = e; jt <= jmax; jt += 3) {
            const bool more = (jt + 3 <= jmax);
            if (more) stageK(jt + 3, cur ^ 1);
            const char* Kc = (const char*)&Ks[cur][0];
            const char* Vc = (const char*)&Vs[0];
            const bool diag = (jt >= 2 * qt);

#pragma unroll
            for (int c32 = 0; c32 < 2; ++c32) {
                // ---- S^T chunk = mfma(K, Q): rows kv (32), cols q (32)
                const int krow = c32 * 32 + lo;
                const int kswz = (krow & 7) << 4;
                bf16x8 ak[4];
#pragma unroll
                for (int dc = 0; dc < 4; ++dc)
                    ak[dc] = *(const bf16x8*)(Kc + krow * 128 + ((dc * 32 + 16 * hi) ^ kswz));
                f32x16 st;
#pragma unroll
                for (int r = 0; r < 16; ++r) st[r] = 0.f;
                __builtin_amdgcn_s_setprio(1);
#pragma unroll
                for (int dc = 0; dc < 4; ++dc)
                    st = __builtin_amdgcn_mfma_f32_32x32x16_bf16(ak[dc], bq[dc], st, 0, 0, 0);
                __builtin_amdgcn_s_setprio(0);

                if (diag) {
                    const int kvb = jt * 64 + c32 * 32 + 4 * hi;
#pragma unroll
                    for (int r = 0; r < 16; ++r)
                        if (kvb + (r & 3) + 8 * (r >> 2) > qg) st[r] = -INFINITY;
                }

                // ---- fixed-max softmax (m = 4, exp2 domain) + in-reg P pack
                bf16x8 paf[2];
                float s = 0.f;
#pragma unroll
                for (int kb = 0; kb < 2; ++kb) {
                    float p[8];
#pragma unroll
                    for (int r = 0; r < 8; ++r) p[r] = exp2f(st[kb * 8 + r] - 4.0f);
                    s += ((p[0] + p[1]) + (p[2] + p[3])) + ((p[4] + p[5]) + (p[6] + p[7]));
                    unsigned int x, zz, y, w;
                    asm("v_cvt_pk_bf16_f32 %0, %1, %2" : "=v"(x)  : "v"(p[0]), "v"(p[1]));
                    asm("v_cvt_pk_bf16_f32 %0, %1, %2" : "=v"(zz) : "v"(p[2]), "v"(p[3]));
                    asm("v_cvt_pk_bf16_f32 %0, %1, %2" : "=v"(y)  : "v"(p[4]), "v"(p[5]));
                    asm("v_cvt_pk_bf16_f32 %0, %1, %2" : "=v"(w)  : "v"(p[6]), "v"(p[7]));
                    asm volatile("v_permlane32_swap_b32 %0, %1" : "+v"(x),  "+v"(y));
                    asm volatile("v_permlane32_swap_b32 %0, %1" : "+v"(zz), "+v"(w));
                    u32x4 aw; aw[0] = x; aw[1] = zz; aw[2] = y; aw[3] = w;
                    paf[kb] = __builtin_bit_cast(bf16x8, aw);
                }
                s += __shfl_xor(s, 32);
                l_run += s;

                if (c32 == 0) {
                    // V(jt) landed gate (own loads) + cross-wave align
                    if (more) { asm volatile("s_waitcnt vmcnt(2)" ::: "memory"); }
                    else      { asm volatile("s_waitcnt vmcnt(0)" ::: "memory"); }
                    __builtin_amdgcn_s_barrier();
                }

                // ---- PV for this chunk
#pragma unroll
                for (int kb = 0; kb < 2; ++kb) {
                    const int vbyte = c32 * 64 + kb * 32 + 16 * hi;
                    const int row0 = lo, row1 = 32 + lo;
                    const bf16x8 vb0 = *(const bf16x8*)(Vc + row0 * 128 + (vbyte ^ ((row0 & 7) << 4)));
                    const bf16x8 vb1 = *(const bf16x8*)(Vc + row1 * 128 + (vbyte ^ ((row1 & 7) << 4)));
                    __builtin_amdgcn_s_setprio(1);
                    oacc0 = __builtin_amdgcn_mfma_f32_32x32x16_bf16(paf[kb], vb0, oacc0, 0, 0, 0);
                    oacc1 = __builtin_amdgcn_mfma_f32_32x32x16_bf16(paf[kb], vb1, oacc1, 0, 0, 0);
                    __builtin_amdgcn_s_setprio(0);
                }
            }

            asm volatile("s_waitcnt vmcnt(0)" ::: "memory");   // K(jt+3) landed
            __builtin_amdgcn_s_barrier();                      // all PV reads done
            if (more) stageV(jt + 3);
            cur ^= 1;
        }

        // ---- epilogue: unnormalized partial O (bf16) + l (f32)
        if (hi == 0) pL[(size_t)(e * 64 + bh) * SEQ + qg] = l_run;
        const size_t pbase = (size_t)bh * SEQ;
#pragma unroll
        for (int rq = 0; rq < 4; ++rq)
#pragma unroll
            for (int ee = 0; ee < 4; ++ee) {
                const int qrow = qw0 + 8 * rq + 4 * hi + ee;
                unsigned short* pr = &pO[(pbase + qrow) * 64];
                pr[lo]      = f2bf(oacc0[rq * 4 + ee]);
                pr[lo + 32] = f2bf(oacc1[rq * 4 + ee]);
            }
    }
}

// ---------------------------------------------------------------------------
// Merge the 3 residue partials (fixed max): O = (O0+O1+O2)/(l0+l1+l2).
// ---------------------------------------------------------------------------
__global__ __launch_bounds__(256)
void attn_merge3(const unsigned short* __restrict__ pO0,
                 const unsigned short* __restrict__ pO1,
                 const unsigned short* __restrict__ pO2,
                 const float* __restrict__ pL,
                 unsigned short* __restrict__ Ctx) {
    const int gid = blockIdx.x * 256 + threadIdx.x;   // 1,048,576 threads
    const int row = gid >> 3;                         // bh*2048 + q
    const int d8  = (gid & 7) * 8;
    const float l0 = pL[row];
    const float l1 = pL[131072 + row];
    const float l2 = pL[262144 + row];
    const float inv = 1.0f / fmaxf(l0 + l1 + l2, 1e-30f);
    const bf16x8 o0 = *(const bf16x8*)&pO0[(size_t)row * 64 + d8];
    const bf16x8 o1 = *(const bf16x8*)&pO1[(size_t)row * 64 + d8];
    const bf16x8 o2 = *(const bf16x8*)&pO2[(size_t)row * 64 + d8];
    const int bh = row >> 11, q = row & 2047;
    unsigned short* dst = &Ctx[((size_t)((bh >> 4) * SEQ + q)) * Dmod + (bh & 15) * DH + d8];
    unsigned short r8[8];
#pragma unroll
    for (int j = 0; j < 8; ++j)
        r8[j] = f2bf((bf2f(o0[j]) + bf2f(o1[j]) + bf2f(o2[j])) * inv);
    *(ushort4*)dst       = make_ushort4(r8[0], r8[1], r8[2], r8[3]);
    *(ushort4*)(dst + 4) = make_ushort4(r8[4], r8[5], r8[6], r8[7]);
}

// ---------------------------------------------------------------------------
extern "C" void kernel_launch(void* const* d_in, const int* in_sizes, int n_in,
                              void* d_out, int out_size, void* d_ws, size_t ws_size,
                              hipStream_t stream) {
    const float* x  = (const float*)d_in[0];
    const float* Wq = (const float*)d_in[1];
    const float* Wk = (const float*)d_in[2];
    const float* Wv = (const float*)d_in[3];
    const float* Wo = (const float*)d_in[4];
    const float* bo = (const float*)d_in[5];
    float* out = (float*)d_out;

    const size_t MD = (size_t)Mtot * Dmod;   // 8,388,608 elems
    const size_t DD = (size_t)Dmod * Dmod;   // 1,048,576 elems
    unsigned short* xb  = (unsigned short*)d_ws;   // [0, 16.78M)  dead after qkv
    unsigned short* wtq = xb  + MD;                 // [16.78M, 18.87M)
    unsigned short* wtk = wtq + DD;                 // [18.87M, 20.97M)
    unsigned short* wtv = wtk + DD;                 // [20.97M, 23.07M)
    unsigned short* wto = wtv + DD;                 // [23.07M, 25.17M) live to end
    unsigned short* Qb  = wto + DD;                 // [25.17M, 41.94M)
    unsigned short* Kb  = Qb  + MD;                 // [41.94M, 58.72M)
    unsigned short* Vtb = Kb  + MD;                 // [58.72M, 75.50M)
    unsigned short* Cx  = Vtb + MD;                 // [75.50M, 92.27M)

    // partial buffers: pO0/pO1 in virgin region after Cx; pO2 reuses the
    // dead xb region (qkv done before attn). pL after pO1.
    const size_t POE = (size_t)64 * SEQ * 64;       // 8.4M elems = 16.78 MB
    unsigned short* pO0 = Cx + MD;                  // [92.27M, 109.05M)
    unsigned short* pO1 = pO0 + POE;                // [109.05M, 125.83M)
    unsigned short* pO2 = (unsigned short*)d_ws;    // [0, 16.78M)
    float*          pL  = (float*)(pO1 + POE);      // [125.83M, 127.40M)

    cvt_bf16<<<2048, 256, 0, stream>>>(x, xb, (int)(MD / 4));
    transpose_cvt4<<<dim3(16, 16, 4), 256, 0, stream>>>(Wq, Wk, Wv, Wo,
                                                        wtq, wtk, wtv, wto);

    // qkv as one 8192 x 3072 GEMM (wtq/wtk/wtv contiguous in ws)
    gemm256<0><<<384, 512, 0, stream>>>(xb, wtq, nullptr, Qb, Kb, Vtb, nullptr);

    attn_mfma<<<1536, 256, 0, stream>>>(Qb, Kb, Vtb, pO0, pO1, pO2, pL);
    attn_merge3<<<4096, 256, 0, stream>>>(pO0, pO1, pO2, pL, Cx);

    gemm256<1><<<256, 512, 0, stream>>>(Cx, wto, bo, nullptr, nullptr, nullptr, out);
}

// Round 19
// 174.436 us; speedup vs baseline: 1.0257x; 1.0257x over previous
//
#include <hip/hip_runtime.h>
#include <hip/hip_bf16.h>
#include <math.h>

typedef __attribute__((ext_vector_type(8))) short bf16x8;   // 8 bf16 = 4 VGPR
typedef __attribute__((ext_vector_type(4))) float f32x4;
typedef __attribute__((ext_vector_type(16))) float f32x16;
typedef __attribute__((ext_vector_type(4))) unsigned int u32x4;

static constexpr int Mtot = 8192;   // B*S
static constexpr int Dmod = 1024;
static constexpr int SEQ  = 2048;
static constexpr int NH   = 16;
static constexpr int DH   = 64;

// softmax scale folded into Q projection, in exp2 domain: (1/8) * log2(e)
static constexpr float QSCALE = 0.18033688011112042f;

// fp32 -> bf16 RNE
__device__ __forceinline__ unsigned short f2bf(float x) {
    unsigned int u = __float_as_uint(x);
    u += 0x7fff + ((u >> 16) & 1);
    return (unsigned short)(u >> 16);
}

__device__ __forceinline__ float bf2f(short s) {
    return __uint_as_float(((unsigned int)(unsigned short)s) << 16);
}

// async global->LDS, 16B per lane. LDS dest = wave-uniform base + lane*16.
__device__ __forceinline__ void gload_lds16(const void* g, void* l) {
    __builtin_amdgcn_global_load_lds(
        (const __attribute__((address_space(1))) unsigned int*)g,
        (__attribute__((address_space(3))) unsigned int*)l, 16, 0, 0);
}

// ---------------------------------------------------------------------------
// x fp32 -> bf16
// ---------------------------------------------------------------------------
__global__ __launch_bounds__(256)
void cvt_bf16(const float* __restrict__ in, unsigned short* __restrict__ out, int n4) {
    int i = blockIdx.x * blockDim.x + threadIdx.x;
    const int stride = gridDim.x * blockDim.x;
    for (; i < n4; i += stride) {
        float4 v = ((const float4*)in)[i];
        ushort4 o;
        o.x = f2bf(v.x); o.y = f2bf(v.y); o.z = f2bf(v.z); o.w = f2bf(v.w);
        ((ushort4*)out)[i] = o;
    }
}

// ---------------------------------------------------------------------------
// All four W[k][n] fp32 -> Wt[n][k] bf16 in one launch (z = which weight)
// ---------------------------------------------------------------------------
__global__ __launch_bounds__(256)
void transpose_cvt4(const float* __restrict__ W0, const float* __restrict__ W1,
                    const float* __restrict__ W2, const float* __restrict__ W3,
                    unsigned short* __restrict__ T0, unsigned short* __restrict__ T1,
                    unsigned short* __restrict__ T2, unsigned short* __restrict__ T3) {
    __shared__ float tile[64][68];
    const int z = blockIdx.z;
    const float* W = z == 0 ? W0 : z == 1 ? W1 : z == 2 ? W2 : W3;
    unsigned short* Wt = z == 0 ? T0 : z == 1 ? T1 : z == 2 ? T2 : T3;

    const int n0 = blockIdx.x * 64, k0 = blockIdx.y * 64;
    const int t = threadIdx.x;
    const int r = t >> 4, c4 = (t & 15) * 4;
#pragma unroll
    for (int i = 0; i < 4; ++i) {
        float4 v = *(const float4*)&W[(size_t)(k0 + r + i * 16) * Dmod + n0 + c4];
        tile[c4 + 0][r + i * 16] = v.x;
        tile[c4 + 1][r + i * 16] = v.y;
        tile[c4 + 2][r + i * 16] = v.z;
        tile[c4 + 3][r + i * 16] = v.w;
    }
    __syncthreads();
#pragma unroll
    for (int i = 0; i < 4; ++i) {
        ushort4 o;
        o.x = f2bf(tile[r + i * 16][c4 + 0]);
        o.y = f2bf(tile[r + i * 16][c4 + 1]);
        o.z = f2bf(tile[r + i * 16][c4 + 2]);
        o.w = f2bf(tile[r + i * 16][c4 + 3]);
        *(ushort4*)&Wt[(size_t)(n0 + r + i * 16) * Dmod + k0 + c4] = o;
    }
}

// ---------------------------------------------------------------------------
// 8-phase GEMM (T3+T4). MODE0: 256x256 tile (qkv, N=3072, 384 blocks).
// MODE1: 128x256 tile (out proj, 256 blocks = full GPU).
// BK=64, 8 waves, LDS dbuf, counted vmcnt (MODE0:6, MODE1:4).
// (round-10 exact configuration — best measured total 174.5 us)
// ---------------------------------------------------------------------------
template<int MODE>
__global__ __launch_bounds__(512)
void gemm256(const unsigned short* __restrict__ A,
             const unsigned short* __restrict__ Bw,
             const float* __restrict__ bias,
             unsigned short* __restrict__ Qb,
             unsigned short* __restrict__ Kb,
             unsigned short* __restrict__ Vtb,
             float* __restrict__ Fout) {
    constexpr int MF   = MODE == 0 ? 8 : 4;        // m-fragments per wave
    constexpr int AHB  = MODE == 0 ? 16384 : 8192; // A half-tile bytes
    constexpr int ALD  = MODE == 0 ? 2 : 1;        // loads per A-stage
    constexpr int OFF_A0 = 0, OFF_B0 = AHB, OFF_A1 = AHB + 16384, OFF_B1 = 2 * AHB + 16384;
    constexpr int BUFB = 2 * AHB + 32768;
    constexpr int NTN  = MODE == 0 ? 12 : 4;
    constexpr int MPX  = MODE == 0 ? 4 : 8;        // m-tiles per XCD

    __shared__ __align__(16) char lds[2 * BUFB];

    const int id  = blockIdx.x;
    const int xcd = id & 7, idx = id >> 3;
    const int mt = xcd * MPX + idx / NTN;
    const int nt = idx % NTN;
    const int m0 = mt * (MF * 32), n0 = nt * 256;

    const int t = threadIdx.x;
    const int wid = t >> 6, l = t & 63;
    const int wm = wid >> 2, wn = wid & 3;
    const int r16 = l & 15, g = l >> 4;

    auto stageA = [&](int kt, int kh, int regionOff) {
        char* dst = lds + regionOff + wid * 1024;
#pragma unroll
        for (int r = 0; r < ALD; ++r) {
            const int o  = r * 8192 + t * 16;
            const int lg = o ^ (((o >> 7) & 3) << 4);
            gload_lds16((const char*)A + (size_t)(m0 + (lg >> 6)) * 2048
                            + kt * 128 + kh * 64 + (lg & 63),
                        dst + r * 8192);
        }
    };
    auto stageB = [&](int kt, int kh, int regionOff) {
        char* dst = lds + regionOff + wid * 1024;
#pragma unroll
        for (int r = 0; r < 2; ++r) {
            const int o  = r * 8192 + t * 16;
            const int lg = o ^ (((o >> 7) & 3) << 4);
            gload_lds16((const char*)Bw + (size_t)(n0 + (lg >> 6)) * 2048
                            + kt * 128 + kh * 64 + (lg & 63),
                        dst + r * 8192);
        }
    };

    f32x4 acc[MF][4];
    const f32x4 z = {0.f, 0.f, 0.f, 0.f};
#pragma unroll
    for (int i = 0; i < MF; ++i)
#pragma unroll
        for (int j = 0; j < 4; ++j) acc[i][j] = z;

    // prologue (issue order fixes vmcnt bookkeeping): A0, B0, A1, B1
    stageA(0, 0, OFF_A0);
    stageB(0, 0, OFF_B0);
    stageA(0, 1, OFF_A1);
    stageB(0, 1, OFF_B1);

    const int arow0 = wm * (MF * 16) + r16;
    const int brow0 = wn * 64 + r16;
    const int gb = g * 16;

    auto gate = [&]() {
        if constexpr (MODE == 0) asm volatile("s_waitcnt vmcnt(6)" ::: "memory");
        else                     asm volatile("s_waitcnt vmcnt(4)" ::: "memory");
        __builtin_amdgcn_s_barrier();
    };

    for (int kt = 0; kt < 16; ++kt) {
        const int buf  = (kt & 1) * BUFB;
        const int nbuf = buf ^ BUFB;
        const int ktn  = kt < 15 ? kt + 1 : 15;   // clamp keeps vmcnt uniform
        bf16x8 af[MF], bv[2];

        // ===== phase 0: kh0, n-frags 0..1 =====
        stageA(ktn, 0, nbuf + OFF_A0);
        gate();
#pragma unroll
        for (int mi = 0; mi < MF; ++mi) {
            const int row = arow0 + mi * 16;
            af[mi] = *(const bf16x8*)(lds + buf + OFF_A0
                      + ((row * 64 + gb) ^ (((row >> 1) & 3) << 4)));
        }
#pragma unroll
        for (int ni = 0; ni < 2; ++ni) {
            const int row = brow0 + ni * 16;
            bv[ni] = *(const bf16x8*)(lds + buf + OFF_B0
                      + ((row * 64 + gb) ^ (((row >> 1) & 3) << 4)));
        }
        asm volatile("s_waitcnt lgkmcnt(0)" ::: "memory");
        __builtin_amdgcn_sched_barrier(0);
        __builtin_amdgcn_s_setprio(1);
#pragma unroll
        for (int mi = 0; mi < MF; ++mi)
#pragma unroll
            for (int ni = 0; ni < 2; ++ni)
                acc[mi][ni] = __builtin_amdgcn_mfma_f32_16x16x32_bf16(
                    af[mi], bv[ni], acc[mi][ni], 0, 0, 0);
        __builtin_amdgcn_s_setprio(0);

        // ===== phase 1: kh0, n-frags 2..3 (reuse af) =====
        stageB(ktn, 0, nbuf + OFF_B0);
#pragma unroll
        for (int ni = 0; ni < 2; ++ni) {
            const int row = brow0 + (2 + ni) * 16;
            bv[ni] = *(const bf16x8*)(lds + buf + OFF_B0
                      + ((row * 64 + gb) ^ (((row >> 1) & 3) << 4)));
        }
        asm volatile("s_waitcnt lgkmcnt(0)" ::: "memory");
        __builtin_amdgcn_sched_barrier(0);
        __builtin_amdgcn_s_setprio(1);
#pragma unroll
        for (int mi = 0; mi < MF; ++mi)
#pragma unroll
            for (int ni = 0; ni < 2; ++ni)
                acc[mi][2 + ni] = __builtin_amdgcn_mfma_f32_16x16x32_bf16(
                    af[mi], bv[ni], acc[mi][2 + ni], 0, 0, 0);
        __builtin_amdgcn_s_setprio(0);

        // ===== phase 2: kh1, n-frags 0..1 =====
        stageA(ktn, 1, nbuf + OFF_A1);
        gate();
#pragma unroll
        for (int mi = 0; mi < MF; ++mi) {
            const int row = arow0 + mi * 16;
            af[mi] = *(const bf16x8*)(lds + buf + OFF_A1
                      + ((row * 64 + gb) ^ (((row >> 1) & 3) << 4)));
        }
#pragma unroll
        for (int ni = 0; ni < 2; ++ni) {
            const int row = brow0 + ni * 16;
            bv[ni] = *(const bf16x8*)(lds + buf + OFF_B1
                      + ((row * 64 + gb) ^ (((row >> 1) & 3) << 4)));
        }
        asm volatile("s_waitcnt lgkmcnt(0)" ::: "memory");
        __builtin_amdgcn_sched_barrier(0);
        __builtin_amdgcn_s_setprio(1);
#pragma unroll
        for (int mi = 0; mi < MF; ++mi)
#pragma unroll
            for (int ni = 0; ni < 2; ++ni)
                acc[mi][ni] = __builtin_amdgcn_mfma_f32_16x16x32_bf16(
                    af[mi], bv[ni], acc[mi][ni], 0, 0, 0);
        __builtin_amdgcn_s_setprio(0);

        // ===== phase 3: kh1, n-frags 2..3 (reuse af) =====
        stageB(ktn, 1, nbuf + OFF_B1);
#pragma unroll
        for (int ni = 0; ni < 2; ++ni) {
            const int row = brow0 + (2 + ni) * 16;
            bv[ni] = *(const bf16x8*)(lds + buf + OFF_B1
                      + ((row * 64 + gb) ^ (((row >> 1) & 3) << 4)));
        }
        asm volatile("s_waitcnt lgkmcnt(0)" ::: "memory");
        __builtin_amdgcn_sched_barrier(0);
        __builtin_amdgcn_s_setprio(1);
#pragma unroll
        for (int mi = 0; mi < MF; ++mi)
#pragma unroll
            for (int ni = 0; ni < 2; ++ni)
                acc[mi][2 + ni] = __builtin_amdgcn_mfma_f32_16x16x32_bf16(
                    af[mi], bv[ni], acc[mi][2 + ni], 0, 0, 0);
        __builtin_amdgcn_s_setprio(0);
    }

    // ===== epilogue =====
    if constexpr (MODE == 0) {
        const int region = n0 >> 10;             // 0=Q, 1=K, 2=V
        if (region <= 1) {
            unsigned short* outp = region ? Kb : Qb;
            const float qs = region == 0 ? QSCALE : 1.0f;
#pragma unroll
            for (int mi = 0; mi < MF; ++mi) {
                const int mrow = m0 + wm * (MF * 16) + mi * 16 + g * 4;
#pragma unroll
                for (int ni = 0; ni < 4; ++ni) {
                    const int ncol = (n0 & 1023) + wn * 64 + ni * 16 + r16;
#pragma unroll
                    for (int reg = 0; reg < 4; ++reg)
                        outp[(size_t)(mrow + reg) * Dmod + ncol] = f2bf(acc[mi][ni][reg] * qs);
                }
            }
        } else {
#pragma unroll
            for (int mi = 0; mi < MF; ++mi) {
                const int mrow = m0 + wm * (MF * 16) + mi * 16 + g * 4;
                const int bidx = mrow >> 11, s = mrow & 2047;
#pragma unroll
                for (int ni = 0; ni < 4; ++ni) {
                    const int n = (n0 & 1023) + wn * 64 + ni * 16 + r16;
                    const int bh = bidx * NH + (n >> 6), d = n & 63;
                    ushort4 o;
                    o.x = f2bf(acc[mi][ni][0]); o.y = f2bf(acc[mi][ni][1]);
                    o.z = f2bf(acc[mi][ni][2]); o.w = f2bf(acc[mi][ni][3]);
                    *(ushort4*)&Vtb[((size_t)bh * DH + d) * SEQ + s] = o;
                }
            }
        }
    } else {
        float bb[4];
#pragma unroll
        for (int ni = 0; ni < 4; ++ni)
            bb[ni] = bias[n0 + wn * 64 + ni * 16 + r16];
#pragma unroll
        for (int mi = 0; mi < MF; ++mi) {
            const int mrow = m0 + wm * (MF * 16) + mi * 16 + g * 4;
#pragma unroll
            for (int ni = 0; ni < 4; ++ni) {
                const int ncol = n0 + wn * 64 + ni * 16 + r16;
#pragma unroll
                for (int reg = 0; reg < 4; ++reg)
                    Fout[(size_t)(mrow + reg) * Dmod + ncol] = acc[mi][ni][reg] + bb[ni];
            }
        }
    }
}

// ---------------------------------------------------------------------------
// MFMA flash attention v5.1 (final: best measured 74.4 us; verified at
// rounds 10, 15, 17). launch_bounds(256,4); fixed-max exp2 softmax; K dbuf
// + V single buffer; counted vmcnt ledger; 2-way parity kv-split.
// Bracketing ledger: (256,5)->VGPR48 spills 117us; (256,3)->78us;
// (256,6)+3way->VGPR40 170us; (256,4)+3way->no residency gain 77us;
// chain-cuts->spill growth 79.6us. This config is the empirical optimum.
// ---------------------------------------------------------------------------
__global__ __launch_bounds__(256, 4)
void attn_mfma(const unsigned short* __restrict__ Qg,
               const unsigned short* __restrict__ Kg,
               const unsigned short* __restrict__ Vtg,
               unsigned short* __restrict__ pO,
               float* __restrict__ pL) {
    __shared__ __align__(16) short Ks[2][64 * 64];   // 16 KB (dbuf)
    __shared__ __align__(16) short Vs[64 * 64];      //  8 KB (single, Vt [d][kv])

    const int id   = blockIdx.x;                   // 0..1023
    const int xcd  = id & 7;
    const int bh   = ((id >> 7) << 3) | xcd;       // XCD-local heads
    const int mid  = (id >> 3) & 15;
    const int pidx = mid >> 1;
    const int par  = mid & 1;                      // kv-tile parity
    const int b = bh >> 4, h = bh & 15;
    const int t = threadIdx.x, wid = t >> 6, l = t & 63;
    const int lo = l & 31, hi = l >> 5;
    const int srow8 = t >> 3, scolb = (t & 7) * 16;

    // per-lane staging base offsets (32-bit: buffers are 16.8 MB)
    unsigned int kbase[2], vbase[2];
#pragma unroll
    for (int c = 0; c < 2; ++c) {
        const int row = c * 32 + srow8;
        const int swz = scolb ^ ((row & 7) << 4);
        kbase[c] = (unsigned int)(((b * SEQ + row) * Dmod + h * DH) * 2 + swz);
        vbase[c] = (unsigned int)(((bh * DH + row) * SEQ) * 2 + swz);
    }

    auto stageK = [&](int jt, int buf) {
#pragma unroll
        for (int c = 0; c < 2; ++c)
            gload_lds16((const char*)Kg + kbase[c] + ((size_t)jt << 17),
                        (char*)&Ks[buf][0] + c * 4096 + wid * 1024);
    };
    auto stageV = [&](int jt) {
#pragma unroll
        for (int c = 0; c < 2; ++c)
            gload_lds16((const char*)Vtg + vbase[c] + ((size_t)jt << 7),
                        (char*)&Vs[0] + c * 4096 + wid * 1024);
    };

    for (int pass = 0; pass < 2; ++pass) {
        const int qt = pass ? pidx : 15 - pidx;   // heavy tile first
        const int qw0 = qt * 128 + wid * 32;
        const int qg = qw0 + lo;                  // this lane's q row (S^T col)
        const int jmax = 2 * qt + 1;

        __syncthreads();                          // prev pass LDS reads done
        // Q fragments straight from global (B-operand: col=q=lane&31, k=d)
        bf16x8 bq[4];
#pragma unroll
        for (int dc = 0; dc < 4; ++dc)
            bq[dc] = *(const bf16x8*)&Qg[(size_t)(b * SEQ + qg) * Dmod + h * DH + dc * 16 + 8 * hi];
        stageK(par, 0);
        stageV(par);
        __syncthreads();                          // vmcnt(0) drain: K,V landed

        float l_run = 0.f;
        f32x16 oacc0, oacc1;
#pragma unroll
        for (int r = 0; r < 16; ++r) { oacc0[r] = 0.f; oacc1[r] = 0.f; }

        int cur = 0;
        for (int jt = par; jt <= jmax; jt += 2) {
            const bool more = (jt + 2 <= jmax);
            if (more) stageK(jt + 2, cur ^ 1);
            const char* Kc = (const char*)&Ks[cur][0];
            const char* Vc = (const char*)&Vs[0];
            const bool diag = (jt >= 2 * qt);

#pragma unroll
            for (int c32 = 0; c32 < 2; ++c32) {
                // ---- S^T chunk = mfma(K, Q): rows kv (32), cols q (32)
                const int krow = c32 * 32 + lo;
                const int kswz = (krow & 7) << 4;
                bf16x8 ak[4];
#pragma unroll
                for (int dc = 0; dc < 4; ++dc)
                    ak[dc] = *(const bf16x8*)(Kc + krow * 128 + ((dc * 32 + 16 * hi) ^ kswz));
                f32x16 st;
#pragma unroll
                for (int r = 0; r < 16; ++r) st[r] = 0.f;
                __builtin_amdgcn_s_setprio(1);
#pragma unroll
                for (int dc = 0; dc < 4; ++dc)
                    st = __builtin_amdgcn_mfma_f32_32x32x16_bf16(ak[dc], bq[dc], st, 0, 0, 0);
                __builtin_amdgcn_s_setprio(0);

                if (diag) {
                    const int kvb = jt * 64 + c32 * 32 + 4 * hi;
#pragma unroll
                    for (int r = 0; r < 16; ++r)
                        if (kvb + (r & 3) + 8 * (r >> 2) > qg) st[r] = -INFINITY;
                }

                // ---- fixed-max softmax (m = 4, exp2 domain) + in-reg P pack
                bf16x8 paf[2];
                float s = 0.f;
#pragma unroll
                for (int kb = 0; kb < 2; ++kb) {
                    float p[8];
#pragma unroll
                    for (int r = 0; r < 8; ++r) p[r] = exp2f(st[kb * 8 + r] - 4.0f);
                    s += ((p[0] + p[1]) + (p[2] + p[3])) + ((p[4] + p[5]) + (p[6] + p[7]));
                    unsigned int x, zz, y, w;
                    asm("v_cvt_pk_bf16_f32 %0, %1, %2" : "=v"(x)  : "v"(p[0]), "v"(p[1]));
                    asm("v_cvt_pk_bf16_f32 %0, %1, %2" : "=v"(zz) : "v"(p[2]), "v"(p[3]));
                    asm("v_cvt_pk_bf16_f32 %0, %1, %2" : "=v"(y)  : "v"(p[4]), "v"(p[5]));
                    asm("v_cvt_pk_bf16_f32 %0, %1, %2" : "=v"(w)  : "v"(p[6]), "v"(p[7]));
                    asm volatile("v_permlane32_swap_b32 %0, %1" : "+v"(x),  "+v"(y));
                    asm volatile("v_permlane32_swap_b32 %0, %1" : "+v"(zz), "+v"(w));
                    u32x4 aw; aw[0] = x; aw[1] = zz; aw[2] = y; aw[3] = w;
                    paf[kb] = __builtin_bit_cast(bf16x8, aw);
                }
                s += __shfl_xor(s, 32);
                l_run += s;

                if (c32 == 0) {
                    // V(jt) landed gate (own loads) + cross-wave align
                    if (more) { asm volatile("s_waitcnt vmcnt(2)" ::: "memory"); }
                    else      { asm volatile("s_waitcnt vmcnt(0)" ::: "memory"); }
                    __builtin_amdgcn_s_barrier();
                }

                // ---- PV for this chunk
#pragma unroll
                for (int kb = 0; kb < 2; ++kb) {
                    const int vbyte = c32 * 64 + kb * 32 + 16 * hi;
                    const int row0 = lo, row1 = 32 + lo;
                    const bf16x8 vb0 = *(const bf16x8*)(Vc + row0 * 128 + (vbyte ^ ((row0 & 7) << 4)));
                    const bf16x8 vb1 = *(const bf16x8*)(Vc + row1 * 128 + (vbyte ^ ((row1 & 7) << 4)));
                    __builtin_amdgcn_s_setprio(1);
                    oacc0 = __builtin_amdgcn_mfma_f32_32x32x16_bf16(paf[kb], vb0, oacc0, 0, 0, 0);
                    oacc1 = __builtin_amdgcn_mfma_f32_32x32x16_bf16(paf[kb], vb1, oacc1, 0, 0, 0);
                    __builtin_amdgcn_s_setprio(0);
                }
            }

            asm volatile("s_waitcnt vmcnt(0)" ::: "memory");   // K(jt+2) landed
            __builtin_amdgcn_s_barrier();                      // all PV reads done
            if (more) stageV(jt + 2);
            cur ^= 1;
        }

        // ---- epilogue: unnormalized partial O (bf16) + l (f32)
        if (hi == 0) pL[(size_t)(par * 64 + bh) * SEQ + qg] = l_run;
        const size_t pbase = (size_t)(par * 64 + bh) * SEQ;
#pragma unroll
        for (int rq = 0; rq < 4; ++rq)
#pragma unroll
            for (int e = 0; e < 4; ++e) {
                const int qrow = qw0 + 8 * rq + 4 * hi + e;
                unsigned short* pr = &pO[(pbase + qrow) * 64];
                pr[lo]      = f2bf(oacc0[rq * 4 + e]);
                pr[lo + 32] = f2bf(oacc1[rq * 4 + e]);
            }
    }
}

// ---------------------------------------------------------------------------
// Merge parity partials (same fixed max): O = (O0 + O1) / (l0 + l1).
// ---------------------------------------------------------------------------
__global__ __launch_bounds__(256)
void attn_merge(const unsigned short* __restrict__ pO,
                const float* __restrict__ pL,
                unsigned short* __restrict__ Ctx) {
    const int gid = blockIdx.x * 256 + threadIdx.x;   // 1,048,576 threads
    const int row = gid >> 3;                         // bh*2048 + q
    const int d8  = (gid & 7) * 8;
    const float l0 = pL[row];
    const float l1 = pL[131072 + row];
    const float inv = 1.0f / fmaxf(l0 + l1, 1e-30f);
    const bf16x8 o0 = *(const bf16x8*)&pO[(size_t)row * 64 + d8];
    const bf16x8 o1 = *(const bf16x8*)&pO[((size_t)131072 + row) * 64 + d8];
    const int bh = row >> 11, q = row & 2047;
    unsigned short* dst = &Ctx[((size_t)((bh >> 4) * SEQ + q)) * Dmod + (bh & 15) * DH + d8];
    unsigned short r8[8];
#pragma unroll
    for (int j = 0; j < 8; ++j)
        r8[j] = f2bf((bf2f(o0[j]) + bf2f(o1[j])) * inv);
    *(ushort4*)dst       = make_ushort4(r8[0], r8[1], r8[2], r8[3]);
    *(ushort4*)(dst + 4) = make_ushort4(r8[4], r8[5], r8[6], r8[7]);
}

// ---------------------------------------------------------------------------
extern "C" void kernel_launch(void* const* d_in, const int* in_sizes, int n_in,
                              void* d_out, int out_size, void* d_ws, size_t ws_size,
                              hipStream_t stream) {
    const float* x  = (const float*)d_in[0];
    const float* Wq = (const float*)d_in[1];
    const float* Wk = (const float*)d_in[2];
    const float* Wv = (const float*)d_in[3];
    const float* Wo = (const float*)d_in[4];
    const float* bo = (const float*)d_in[5];
    float* out = (float*)d_out;

    const size_t MD = (size_t)Mtot * Dmod;   // 8,388,608 elems
    const size_t DD = (size_t)Dmod * Dmod;   // 1,048,576 elems
    unsigned short* xb  = (unsigned short*)d_ws;   // [0, 16.78M)
    unsigned short* wtq = xb  + MD;                 // [16.78M, 18.87M)
    unsigned short* wtk = wtq + DD;                 // [18.87M, 20.97M)
    unsigned short* wtv = wtk + DD;                 // [20.97M, 23.07M)
    unsigned short* wto = wtv + DD;                 // [23.07M, 25.17M) live to end
    unsigned short* Qb  = wto + DD;                 // [25.17M, 41.94M)
    unsigned short* Kb  = Qb  + MD;                 // [41.94M, 58.72M)
    unsigned short* Vtb = Kb  + MD;                 // [58.72M, 75.50M)
    unsigned short* Cx  = Vtb + MD;                 // [75.50M, 92.27M)

    // partials in virgin region after Cx: pO 33.55 MB, pL 1.05 MB
    unsigned short* pO = Cx + MD;
    float*          pL = (float*)(pO + (size_t)2 * 64 * SEQ * 64);

    cvt_bf16<<<2048, 256, 0, stream>>>(x, xb, (int)(MD / 4));
    transpose_cvt4<<<dim3(16, 16, 4), 256, 0, stream>>>(Wq, Wk, Wv, Wo,
                                                        wtq, wtk, wtv, wto);

    // qkv as one 8192 x 3072 GEMM (wtq/wtk/wtv contiguous in ws)
    gemm256<0><<<384, 512, 0, stream>>>(xb, wtq, nullptr, Qb, Kb, Vtb, nullptr);

    attn_mfma<<<1024, 256, 0, stream>>>(Qb, Kb, Vtb, pO, pL);
    attn_merge<<<4096, 256, 0, stream>>>(pO, pL, Cx);

    gemm256<1><<<256, 512, 0, stream>>>(Cx, wto, bo, nullptr, nullptr, nullptr, out);
}